// Round 7
// baseline (288.026 us; speedup 1.0000x reference)
//
#include <hip/hip_runtime.h>
#include <math.h>

#define N_ROWS 32768
#define K_CODES 4096
#define DIM 64
#define WAVES 8
#define TILES_TOTAL (K_CODES / 32)            // 128
#define TILES_PER_WAVE (TILES_TOTAL / WAVES)  // 16
#define QUANT_ELEMS (N_ROWS * DIM)            // 2097152

typedef _Float16 half8 __attribute__((ext_vector_type(8)));
typedef float floatx16 __attribute__((ext_vector_type(16)));

#define MFMA32(a, b, c) __builtin_amdgcn_mfma_f32_32x32x16_f16((a), (b), (c), 0, 0, 0)

// ---------------------------------------------------------------------------
// Kernel 0 (fused): embed -> fp16 hi/lo B-fragments for mfma_f32_32x32x16_f16
// AND per-code squared norms (LDS reduction).
// Tile c = 32 codes; kstep s covers k=16s..16s+15. Thread t = c*256 + s*64 + l
// holds B[k=(l>>5)*8+j+16s][col=l&31] = embed[c*32+(l&31)][(l>>5)*8+j+16s].
// One 256-thread block per tile (grid = 128 blocks).
// ---------------------------------------------------------------------------
__global__ void prep_kernel(const float* __restrict__ embed,
                            float* __restrict__ sq, half8* __restrict__ ehi,
                            half8* __restrict__ elo) {
    __shared__ float part[256];
    const int tid = threadIdx.x;
    const int t = blockIdx.x * 256 + tid;
    const int l = t & 63;
    const int s = (t >> 6) & 3;
    const int c = blockIdx.x;
    const int col = l & 31;
    const int code = c * 32 + col;
    const int koff = (l >> 5) * 8 + 16 * s;
    const float* src = embed + (size_t)code * DIM + koff;
    half8 h, lo;
    float ss = 0.f;
#pragma unroll
    for (int j = 0; j < 8; ++j) {
        float v = src[j];
        ss = fmaf(v, v, ss);
        _Float16 hi = (_Float16)v;
        h[j] = hi;
        lo[j] = (_Float16)(v - (float)hi);
    }
    ehi[t] = h;
    elo[t] = lo;
    part[tid] = ss;
    __syncthreads();
    if (tid < 32) {
        float a = 0.f;
#pragma unroll
        for (int q = 0; q < 8; ++q)
            a += part[tid + 32 * (q & 1) + 64 * (q >> 1)];
        sq[c * 32 + tid] = a;
    }
}

// ---------------------------------------------------------------------------
// Kernel 1: fully fused dist(GEMM 32x32x16) + argmax + combine + gather.
// Block = 8 waves (512 thr) over the SAME 64 rows; wave w sweeps tiles
// [w*16,(w+1)*16) with register double-buffered B (L2 -> VGPR, no LDS in
// the hot loop). grid = 512 blocks = 2 blocks/CU = 16 waves/CU = 4/SIMD.
// dist = dot(2x,e) - ||e||^2 ; -||e||^2 = acc init, 2x folded into A (exact).
// fp16 split, 3 terms: xh*eh + xl*eh + xh*el.
// ---------------------------------------------------------------------------
#define LOADTILE(buf, c)                                                     \
    {                                                                        \
        const int cc = (c);                                                  \
        const half8* p = ehi + (size_t)(c0 + cc) * 256 + lane;               \
        bh##buf[0] = p[0];                                                   \
        bh##buf[1] = p[64];                                                  \
        bh##buf[2] = p[128];                                                 \
        bh##buf[3] = p[192];                                                 \
        const half8* q = elo + (size_t)(c0 + cc) * 256 + lane;               \
        bl##buf[0] = q[0];                                                   \
        bl##buf[1] = q[64];                                                  \
        bl##buf[2] = q[128];                                                 \
        bl##buf[3] = q[192];                                                 \
        nsq##buf = -sq[(size_t)(c0 + cc) * 32 + col];                        \
    }

#define COMPUTETILE(buf, c)                                                  \
    {                                                                        \
        floatx16 acc0, acc1;                                                 \
        _Pragma("unroll") for (int r = 0; r < 16; ++r) {                     \
            acc0[r] = nsq##buf;                                              \
            acc1[r] = nsq##buf;                                              \
        }                                                                    \
        _Pragma("unroll") for (int s = 0; s < 4; ++s) {                      \
            acc0 = MFMA32(ah[0][s], bh##buf[s], acc0);                       \
            acc1 = MFMA32(ah[1][s], bh##buf[s], acc1);                       \
            acc0 = MFMA32(al[0][s], bh##buf[s], acc0);                       \
            acc1 = MFMA32(al[1][s], bh##buf[s], acc1);                       \
            acc0 = MFMA32(ah[0][s], bl##buf[s], acc0);                       \
            acc1 = MFMA32(ah[1][s], bl##buf[s], acc1);                       \
        }                                                                    \
        const int cidx = (c0 + (c)) * 32 + col;                              \
        _Pragma("unroll") for (int r = 0; r < 16; ++r) {                     \
            if (acc0[r] > best0[r]) { /* strict >: earliest wins ties */     \
                best0[r] = acc0[r];                                          \
                idx0[r] = cidx;                                              \
            }                                                                \
            if (acc1[r] > best1[r]) {                                        \
                best1[r] = acc1[r];                                          \
                idx1[r] = cidx;                                              \
            }                                                                \
        }                                                                    \
    }

__global__ __launch_bounds__(512, 4) void fused_all(
    const float* __restrict__ x, const float* __restrict__ sq,
    const half8* __restrict__ ehi, const half8* __restrict__ elo,
    const float* __restrict__ embed, float* __restrict__ out) {
    __shared__ float rbest[WAVES][64];
    __shared__ int ridx[WAVES][64];
    __shared__ int fidx[64];

    const int tid = threadIdx.x;
    const int lane = tid & 63;
    const int wave = tid >> 6;
    const int col = lane & 31;    // B col (code within tile); A row
    const int half_ = lane >> 5;  // k-half
    const int row_base = blockIdx.x * 64;

    // Persistent A fragments, two 32-row subtiles, scaled by 2 (exact).
    // A[m=col (+32*m)][k = half_*8 + j + 16*s]
    half8 ah[2][4], al[2][4];
#pragma unroll
    for (int m = 0; m < 2; ++m) {
        const float* xs =
            x + (size_t)(row_base + m * 32 + col) * DIM + half_ * 8;
#pragma unroll
        for (int s = 0; s < 4; ++s) {
            half8 h, lo;
#pragma unroll
            for (int j = 0; j < 8; ++j) {
                float v = 2.0f * xs[16 * s + j];
                _Float16 hi = (_Float16)v;
                h[j] = hi;
                lo[j] = (_Float16)(v - (float)hi);
            }
            ah[m][s] = h;
            al[m][s] = lo;
        }
    }

    float best0[16], best1[16];
    int idx0[16], idx1[16];
#pragma unroll
    for (int r = 0; r < 16; ++r) {
        best0[r] = -INFINITY;
        best1[r] = -INFINITY;
        idx0[r] = 0;
        idx1[r] = 0;
    }

    const int c0 = wave * TILES_PER_WAVE;
    half8 bh0[4], bl0[4], bh1[4], bl1[4];
    float nsq0, nsq1;

    LOADTILE(0, 0)
    // Pipelined sweep: load (c+1) while computing c. Ascending c order is
    // preserved, so tie-break (strict >) still matches jnp.argmax.
    for (int c = 0; c < TILES_PER_WAVE; c += 2) {
        LOADTILE(1, c + 1)
        COMPUTETILE(0, c)
        LOADTILE(0, c + 2 < TILES_PER_WAVE ? c + 2 : TILES_PER_WAVE - 1)
        COMPUTETILE(1, c + 1)
    }

    // C/D layout (32x32): col = lane&31, row = (r&3) + 8*(r>>2) + 4*half_.
    // Butterfly over the 32 lanes of each half (cols), stash per-wave winners.
#pragma unroll
    for (int r = 0; r < 16; ++r) {
        const int row = (r & 3) + 8 * (r >> 2) + 4 * half_;
        float bv = best0[r];
        int bi = idx0[r];
#pragma unroll
        for (int d = 1; d < 32; d <<= 1) {
            float ov = __shfl_xor(bv, d);
            int oi = __shfl_xor(bi, d);
            if (ov > bv || (ov == bv && oi < bi)) {  // smaller idx on tie
                bv = ov;
                bi = oi;
            }
        }
        if (col == 0) {
            rbest[wave][row] = bv;
            ridx[wave][row] = bi;
        }
        bv = best1[r];
        bi = idx1[r];
#pragma unroll
        for (int d = 1; d < 32; d <<= 1) {
            float ov = __shfl_xor(bv, d);
            int oi = __shfl_xor(bi, d);
            if (ov > bv || (ov == bv && oi < bi)) {
                bv = ov;
                bi = oi;
            }
        }
        if (col == 0) {
            rbest[wave][row + 32] = bv;
            ridx[wave][row + 32] = bi;
        }
    }
    __syncthreads();

    // Cross-wave combine: wave order == ascending code ranges, so strict >
    // preserves jnp.argmax first-max semantics.
    if (tid < 64) {
        float bv = rbest[0][tid];
        int bi = ridx[0][tid];
#pragma unroll
        for (int w = 1; w < WAVES; ++w) {
            float b = rbest[w][tid];
            if (b > bv) {
                bv = b;
                bi = ridx[w][tid];
            }
        }
        fidx[tid] = bi;
        out[(size_t)QUANT_ELEMS + row_base + tid] = (float)bi;
    }
    __syncthreads();

    // Gather + write quantize: 512 threads x 2 float4 chunks = 64 rows x 64f.
    const int grow = tid >> 3;
    const int q0 = tid & 7;
    const int bi = fidx[grow];
    const float4* e4 = reinterpret_cast<const float4*>(embed);
    float4* o4 = reinterpret_cast<float4*>(out);
#pragma unroll
    for (int q = 0; q < 2; ++q) {
        const int chunk = q0 + 8 * q;
        o4[(size_t)(row_base + grow) * (DIM / 4) + chunk] =
            e4[(size_t)bi * (DIM / 4) + chunk];
    }
}

// ---------------------------------------------------------------------------
extern "C" void kernel_launch(void* const* d_in, const int* in_sizes, int n_in,
                              void* d_out, int out_size, void* d_ws,
                              size_t ws_size, hipStream_t stream) {
    const float* x = (const float*)d_in[0];
    const float* embed = (const float*)d_in[1];
    float* out = (float*)d_out;

    // ws: sq 16KB | ehi 512KB | elo 512KB
    char* ws = (char*)d_ws;
    float* sq = (float*)ws;
    half8* ehi = (half8*)(ws + 16384);
    half8* elo = (half8*)(ws + 16384 + 524288);

    prep_kernel<<<TILES_TOTAL, 256, 0, stream>>>(embed, sq, ehi, elo);

    fused_all<<<N_ROWS / 64, 512, 0, stream>>>(x, sq, ehi, elo, embed, out);
}

// Round 8
// 126.958 us; speedup vs baseline: 2.2687x; 2.2687x over previous
//
#include <hip/hip_runtime.h>
#include <math.h>

#define N_ROWS 32768
#define K_CODES 4096
#define DIM 64
#define SPLITS 4
#define TILES_TOTAL (K_CODES / 32)              // 128
#define TILES_PER_SPLIT (TILES_TOTAL / SPLITS)  // 32
#define QUANT_ELEMS (N_ROWS * DIM)              // 2097152

typedef _Float16 half8 __attribute__((ext_vector_type(8)));
typedef float floatx16 __attribute__((ext_vector_type(16)));

#define MFMA32(a, b, c) __builtin_amdgcn_mfma_f32_32x32x16_f16((a), (b), (c), 0, 0, 0)

// async global->LDS, 16 B per lane (wave-uniform base + lane*16 layout)
__device__ __forceinline__ void gld16(const void* g, void* l) {
    __builtin_amdgcn_global_load_lds(
        (const __attribute__((address_space(1))) unsigned int*)g,
        (__attribute__((address_space(3))) unsigned int*)l, 16, 0, 0);
}

// ---------------------------------------------------------------------------
// Kernel 0 (fused): embed -> fp16 hi/lo B-fragments for mfma_f32_32x32x16_f16
// AND per-code squared norms (LDS reduction).
// Tile c = 32 codes; kstep s covers k=16s..16s+15. Thread t = c*256 + s*64 + l
// holds B[k=(l>>5)*8+j+16s][col=l&31] = embed[c*32+(l&31)][(l>>5)*8+j+16s].
// One 256-thread block per tile (grid = 128 blocks).
// ---------------------------------------------------------------------------
__global__ void prep_kernel(const float* __restrict__ embed,
                            float* __restrict__ sq, half8* __restrict__ ehi,
                            half8* __restrict__ elo) {
    __shared__ float part[256];
    const int tid = threadIdx.x;
    const int t = blockIdx.x * 256 + tid;
    const int l = t & 63;
    const int s = (t >> 6) & 3;
    const int c = blockIdx.x;
    const int col = l & 31;
    const int code = c * 32 + col;
    const int koff = (l >> 5) * 8 + 16 * s;
    const float* src = embed + (size_t)code * DIM + koff;
    half8 h, lo;
    float ss = 0.f;
#pragma unroll
    for (int j = 0; j < 8; ++j) {
        float v = src[j];
        ss = fmaf(v, v, ss);
        _Float16 hi = (_Float16)v;
        h[j] = hi;
        lo[j] = (_Float16)(v - (float)hi);
    }
    ehi[t] = h;
    elo[t] = lo;
    part[tid] = ss;
    __syncthreads();
    if (tid < 32) {
        float a = 0.f;
#pragma unroll
        for (int q = 0; q < 8; ++q)
            a += part[tid + 32 * (q & 1) + 64 * (q >> 1)];
        sq[c * 32 + tid] = a;
    }
}

// ---------------------------------------------------------------------------
// Kernel 1: fused dist(GEMM 32x32x16) + per-split argmax.
// M=32 rows/wave (lean registers: ~124 VGPR -> 4 waves/SIMD), 4 waves/block
// share each 8 KB B tile via LDS, DOUBLE-BUFFERED with ONE barrier per tile:
//   ds_read tile c -> prefetch tile c+1 (global_load_lds) -> 12 MFMA +
//   compares -> __syncthreads() (its vmcnt(0) drain lands after ~770 cyc of
//   MFMA, so the prefetch is free).
// dist = dot(2x,e) - ||e||^2 ; -||e||^2 = acc init, 2x folded into A (exact).
// fp16 split, 3 terms: xh*eh + xl*eh + xh*el.
// grid = (N_ROWS/128, SPLITS) = (256,4) = 1024 blocks = 4 blocks/CU.
// ---------------------------------------------------------------------------
__global__ __launch_bounds__(256, 4) void fused_dist_argmax32(
    const float* __restrict__ x, const float* __restrict__ sq,
    const half8* __restrict__ ehi, const half8* __restrict__ elo,
    float* __restrict__ pbest, int* __restrict__ pidx) {
    __shared__ char lbuf[2][8192];  // per buf: [0,4K)=hi, [4K,8K)=lo
    const int tid = threadIdx.x;
    const int lane = tid & 63;
    const int wave = tid >> 6;
    const int col = lane & 31;    // B col (code within tile); A row
    const int half_ = lane >> 5;  // k-half
    const int row_base = blockIdx.x * 128 + wave * 32;
    const int split = blockIdx.y;
    const int c0 = split * TILES_PER_SPLIT;

    // Persistent A fragments (scaled by 2, exact): A[m=col][k=half_*8+j+16s]
    half8 ah[4], al[4];
    {
        const float* xs = x + (size_t)(row_base + col) * DIM + half_ * 8;
#pragma unroll
        for (int s = 0; s < 4; ++s) {
            half8 h, lo;
#pragma unroll
            for (int j = 0; j < 8; ++j) {
                float v = 2.0f * xs[16 * s + j];
                _Float16 hi = (_Float16)v;
                h[j] = hi;
                lo[j] = (_Float16)(v - (float)hi);
            }
            ah[s] = h;
            al[s] = lo;
        }
    }

    float best[16];
    int bidx[16];
#pragma unroll
    for (int r = 0; r < 16; ++r) {
        best[r] = -INFINITY;
        bidx[r] = 0;
    }

    const char* gh = (const char*)(ehi + (size_t)c0 * 256);
    const char* gl = (const char*)(elo + (size_t)c0 * 256);
    const float* psq = sq + c0 * 32 + col;

    // Preload tile 0 into buf 0.
    gld16(gh + (size_t)tid * 16, lbuf[0] + tid * 16);
    gld16(gl + (size_t)tid * 16, lbuf[0] + 4096 + tid * 16);
    __syncthreads();  // vmcnt(0) drain: tile 0 resident

    for (int c = 0; c < TILES_PER_SPLIT; ++c) {
        const int cur = c & 1;
        const half8* lh = (const half8*)(lbuf[cur]);
        const half8* ll = (const half8*)(lbuf[cur] + 4096);

        // LDS -> registers (ds_read_b128 x8), then prefetch next tile.
        half8 bh0 = lh[lane], bh1 = lh[64 + lane], bh2 = lh[128 + lane],
              bh3 = lh[192 + lane];
        half8 bl0 = ll[lane], bl1 = ll[64 + lane], bl2 = ll[128 + lane],
              bl3 = ll[192 + lane];
        float nsq = -psq[(size_t)c * 32];

        if (c + 1 < TILES_PER_SPLIT) {
            const size_t off = (size_t)(c + 1) * 4096 + (size_t)tid * 16;
            gld16(gh + off, lbuf[cur ^ 1] + tid * 16);
            gld16(gl + off, lbuf[cur ^ 1] + 4096 + tid * 16);
        }

        floatx16 acc;
#pragma unroll
        for (int r = 0; r < 16; ++r) acc[r] = nsq;
        acc = MFMA32(ah[0], bh0, acc);
        acc = MFMA32(al[0], bh0, acc);
        acc = MFMA32(ah[0], bl0, acc);
        acc = MFMA32(ah[1], bh1, acc);
        acc = MFMA32(al[1], bh1, acc);
        acc = MFMA32(ah[1], bl1, acc);
        acc = MFMA32(ah[2], bh2, acc);
        acc = MFMA32(al[2], bh2, acc);
        acc = MFMA32(ah[2], bl2, acc);
        acc = MFMA32(ah[3], bh3, acc);
        acc = MFMA32(al[3], bh3, acc);
        acc = MFMA32(ah[3], bl3, acc);

        const int cidx = (c0 + c) * 32 + col;
#pragma unroll
        for (int r = 0; r < 16; ++r) {
            if (acc[r] > best[r]) {  // strict >: earliest tile wins ties
                best[r] = acc[r];
                bidx[r] = cidx;
            }
        }
        // Single barrier: (a) everyone done ds_reading buf[cur] -> safe to
        // overwrite next iter; (b) compiler's vmcnt(0) drain certifies the
        // prefetch landed -> buf[cur^1] ready. Lands after 12 MFMAs.
        __syncthreads();
    }

    // C/D layout (32x32): col = lane&31, row = (r&3) + 8*(r>>2) + 4*half_.
#pragma unroll
    for (int r = 0; r < 16; ++r) {
        float bv = best[r];
        int bi = bidx[r];
#pragma unroll
        for (int d = 1; d < 32; d <<= 1) {
            float ov = __shfl_xor(bv, d);
            int oi = __shfl_xor(bi, d);
            if (ov > bv || (ov == bv && oi < bi)) {  // smaller idx on tie
                bv = ov;
                bi = oi;
            }
        }
        if (col == 0) {
            const int row = row_base + (r & 3) + 8 * (r >> 2) + 4 * half_;
            pbest[(size_t)split * N_ROWS + row] = bv;
            pidx[(size_t)split * N_ROWS + row] = bi;
        }
    }
}

// ---------------------------------------------------------------------------
// Kernel 2: combine splits, gather quantize rows, write index-as-float.
// One thread per (row, float4-chunk): t in [0, N_ROWS*16).
// ---------------------------------------------------------------------------
__global__ void combine_kernel(const float* __restrict__ pbest,
                               const int* __restrict__ pidx,
                               const float* __restrict__ embed,
                               float* __restrict__ out) {
    const int t = blockIdx.x * blockDim.x + threadIdx.x;
    const int row = t >> 4;
    const int q = t & 15;
    if (row >= N_ROWS) return;

    float best = -INFINITY;
    int bi = 0;
#pragma unroll
    for (int s = 0; s < SPLITS; ++s) {
        float b = pbest[(size_t)s * N_ROWS + row];
        int i = pidx[(size_t)s * N_ROWS + row];
        if (b > best) {  // splits ascending in k; strict > keeps earliest
            best = b;
            bi = i;
        }
    }

    const float4* e4 = reinterpret_cast<const float4*>(embed);
    float4 v = e4[(size_t)bi * (DIM / 4) + q];
    reinterpret_cast<float4*>(out)[(size_t)row * (DIM / 4) + q] = v;
    if (q == 0) {
        out[(size_t)QUANT_ELEMS + row] = (float)bi;  // index as float
    }
}

// ---------------------------------------------------------------------------
extern "C" void kernel_launch(void* const* d_in, const int* in_sizes, int n_in,
                              void* d_out, int out_size, void* d_ws,
                              size_t ws_size, hipStream_t stream) {
    const float* x = (const float*)d_in[0];
    const float* embed = (const float*)d_in[1];
    float* out = (float*)d_out;

    // ws: sq 16KB | ehi 512KB | elo 512KB | pbest 512KB | pidx 512KB
    char* ws = (char*)d_ws;
    float* sq = (float*)ws;
    half8* ehi = (half8*)(ws + 16384);
    half8* elo = (half8*)(ws + 16384 + 524288);
    float* pbest = (float*)(ws + 16384 + 2 * 524288);
    int* pidx = (int*)(ws + 16384 + 2 * 524288 + SPLITS * N_ROWS * 4);

    prep_kernel<<<TILES_TOTAL, 256, 0, stream>>>(embed, sq, ehi, elo);

    dim3 grid(N_ROWS / 128, SPLITS);
    fused_dist_argmax32<<<grid, 256, 0, stream>>>(x, sq, ehi, elo, pbest,
                                                  pidx);

    const int combine_threads = N_ROWS * (DIM / 4);
    combine_kernel<<<(combine_threads + 255) / 256, 256, 0, stream>>>(
        pbest, pidx, embed, out);
}

// Round 9
// 123.718 us; speedup vs baseline: 2.3281x; 1.0262x over previous
//
#include <hip/hip_runtime.h>
#include <math.h>

#define N_ROWS 32768
#define K_CODES 4096
#define DIM 64
#define SPLITS 3
#define TILES_TOTAL (K_CODES / 32)   // 128 -> splits of 44/42/42 (all even)
#define QUANT_ELEMS (N_ROWS * DIM)   // 2097152

typedef _Float16 half8 __attribute__((ext_vector_type(8)));
typedef float floatx16 __attribute__((ext_vector_type(16)));

#define MFMA32(a, b, c) __builtin_amdgcn_mfma_f32_32x32x16_f16((a), (b), (c), 0, 0, 0)

// async global->LDS, 16 B per lane (wave-uniform base + lane*16 layout)
__device__ __forceinline__ void gld16(const void* g, void* l) {
    __builtin_amdgcn_global_load_lds(
        (const __attribute__((address_space(1))) unsigned int*)g,
        (__attribute__((address_space(3))) unsigned int*)l, 16, 0, 0);
}

// ---------------------------------------------------------------------------
// Kernel 0 (fused): embed -> fp16 hi/lo B-fragments for mfma_f32_32x32x16_f16
// AND per-code squared norms (LDS reduction). One 256-thr block per 32-code
// tile; thread t = c*256 + s*64 + l holds
// B[k=(l>>5)*8+j+16s][col=l&31] = embed[c*32+(l&31)][(l>>5)*8+j+16s].
// ---------------------------------------------------------------------------
__global__ void prep_kernel(const float* __restrict__ embed,
                            float* __restrict__ sq, half8* __restrict__ ehi,
                            half8* __restrict__ elo) {
    __shared__ float part[256];
    const int tid = threadIdx.x;
    const int t = blockIdx.x * 256 + tid;
    const int l = t & 63;
    const int s = (t >> 6) & 3;
    const int c = blockIdx.x;
    const int col = l & 31;
    const int code = c * 32 + col;
    const int koff = (l >> 5) * 8 + 16 * s;
    const float* src = embed + (size_t)code * DIM + koff;
    half8 h, lo;
    float ss = 0.f;
#pragma unroll
    for (int j = 0; j < 8; ++j) {
        float v = src[j];
        ss = fmaf(v, v, ss);
        _Float16 hi = (_Float16)v;
        h[j] = hi;
        lo[j] = (_Float16)(v - (float)hi);
    }
    ehi[t] = h;
    elo[t] = lo;
    part[tid] = ss;
    __syncthreads();
    if (tid < 32) {
        float a = 0.f;
#pragma unroll
        for (int q = 0; q < 8; ++q)
            a += part[tid + 32 * (q & 1) + 64 * (q >> 1)];
        sq[c * 32 + tid] = a;
    }
}

// One tile's 12-MFMA chain from LDS buffer `buf` into acc `A`.
#define TILECOMPUTE(A, buf, cc)                                              \
    {                                                                        \
        const half8* lh = (const half8*)(buf);                               \
        const half8* ll = (const half8*)((buf) + 4096);                      \
        half8 b0 = lh[lane], b1 = lh[64 + lane], b2 = lh[128 + lane],        \
              b3 = lh[192 + lane];                                           \
        half8 l0 = ll[lane], l1 = ll[64 + lane], l2 = ll[128 + lane],        \
              l3 = ll[192 + lane];                                           \
        float nsq = -psq[(size_t)(cc) * 32];                                 \
        _Pragma("unroll") for (int r = 0; r < 16; ++r) A[r] = nsq;           \
        A = MFMA32(ah[0], b0, A);                                            \
        A = MFMA32(al[0], b0, A);                                            \
        A = MFMA32(ah[0], l0, A);                                            \
        A = MFMA32(ah[1], b1, A);                                            \
        A = MFMA32(al[1], b1, A);                                            \
        A = MFMA32(ah[1], l1, A);                                            \
        A = MFMA32(ah[2], b2, A);                                            \
        A = MFMA32(al[2], b2, A);                                            \
        A = MFMA32(ah[2], l2, A);                                            \
        A = MFMA32(ah[3], b3, A);                                            \
        A = MFMA32(al[3], b3, A);                                            \
        A = MFMA32(ah[3], l3, A);                                            \
    }

// ---------------------------------------------------------------------------
// Kernel 1: fused dist(GEMM 32x32x16) + per-split argmax.
// M=32/wave; 4 waves share LDS-staged B. TWO tiles per iteration: two
// independent MFMA chains (acc0/acc1), compares after both, ONE barrier per
// 2 tiles. 4 LDS buffers (32 KB): iteration {c,c+1} reads buf pair
// {c&3,(c+1)&3} while DMA fills the other pair with {c+2,c+3}; the
// end-of-iteration barrier's vmcnt(0) drain lands after ~24 MFMA + compares.
// dist = dot(2x,e) - ||e||^2 (acc init = -||e||^2, 2x folded into A, exact).
// fp16 split, 3 terms: xh*eh + xl*eh + xh*el.
// grid = (256, 3) = 768 blocks = exactly 3 blocks/CU (launch_bounds(256,3),
// reg cap ~170 >= ~150 used -> no spill, no tail wave).
// Splits: tiles [0,44), [44,86), [86,128) — ascending, all even-sized.
// ---------------------------------------------------------------------------
__global__ __launch_bounds__(256, 3) void fused_dist_argmax32(
    const float* __restrict__ x, const float* __restrict__ sq,
    const half8* __restrict__ ehi, const half8* __restrict__ elo,
    float* __restrict__ pbest, int* __restrict__ pidx) {
    __shared__ char lbuf[4][8192];  // per buf: [0,4K)=hi, [4K,8K)=lo
    const int tid = threadIdx.x;
    const int lane = tid & 63;
    const int wave = tid >> 6;
    const int col = lane & 31;    // B col (code within tile); A row
    const int half_ = lane >> 5;  // k-half
    const int row_base = blockIdx.x * 128 + wave * 32;
    const int split = blockIdx.y;
    const int c0 = (split == 0) ? 0 : ((split == 1) ? 44 : 86);
    const int nt = (split == 0) ? 44 : 42;

    // Persistent A fragments (scaled by 2, exact): A[m=col][k=half_*8+j+16s]
    half8 ah[4], al[4];
    {
        const float* xs = x + (size_t)(row_base + col) * DIM + half_ * 8;
#pragma unroll
        for (int s = 0; s < 4; ++s) {
            half8 h, lo;
#pragma unroll
            for (int j = 0; j < 8; ++j) {
                float v = 2.0f * xs[16 * s + j];
                _Float16 hi = (_Float16)v;
                h[j] = hi;
                lo[j] = (_Float16)(v - (float)hi);
            }
            ah[s] = h;
            al[s] = lo;
        }
    }

    float best[16];
    int bidx[16];
#pragma unroll
    for (int r = 0; r < 16; ++r) {
        best[r] = -INFINITY;
        bidx[r] = 0;
    }

    const char* gh = (const char*)(ehi + (size_t)c0 * 256);
    const char* gl = (const char*)(elo + (size_t)c0 * 256);
    const float* psq = sq + c0 * 32 + col;

    // Prologue: tiles 0,1 -> bufs 0,1.
    {
        const size_t o = (size_t)tid * 16;
        gld16(gh + o, lbuf[0] + tid * 16);
        gld16(gl + o, lbuf[0] + 4096 + tid * 16);
        gld16(gh + 4096 + o, lbuf[1] + tid * 16);
        gld16(gl + 4096 + o, lbuf[1] + 4096 + tid * 16);
    }
    __syncthreads();  // vmcnt(0) drain: tiles 0,1 resident

    for (int c = 0; c < nt; c += 2) {
        // Prefetch tiles c+2, c+3 into the buffer pair NOT being read this
        // iteration (freed by the previous iteration's barrier).
        if (c + 2 < nt) {  // nt even => covers c+3 too
            const size_t o2 = (size_t)(c + 2) * 4096 + (size_t)tid * 16;
            char* d2 = lbuf[(c + 2) & 3];
            gld16(gh + o2, d2 + tid * 16);
            gld16(gl + o2, d2 + 4096 + tid * 16);
            const size_t o3 = o2 + 4096;
            char* d3 = lbuf[(c + 3) & 3];
            gld16(gh + o3, d3 + tid * 16);
            gld16(gl + o3, d3 + 4096 + tid * 16);
        }

        floatx16 acc0, acc1;
        TILECOMPUTE(acc0, lbuf[c & 3], c)
        TILECOMPUTE(acc1, lbuf[(c + 1) & 3], c + 1)

        // Compares: tile c first, then c+1 (ascending order + strict > keeps
        // the earliest max, matching jnp.argmax).
        const int cidx0 = (c0 + c) * 32 + col;
#pragma unroll
        for (int r = 0; r < 16; ++r) {
            if (acc0[r] > best[r]) {
                best[r] = acc0[r];
                bidx[r] = cidx0;
            }
            if (acc1[r] > best[r]) {
                best[r] = acc1[r];
                bidx[r] = cidx0 + 32;
            }
        }
        // Barrier: (a) all waves done reading bufs {c,c+1} -> safe to refill
        // next iteration; (b) vmcnt(0) drain certifies prefetch landed.
        __syncthreads();
    }

    // C/D layout (32x32): col = lane&31, row = (r&3) + 8*(r>>2) + 4*half_.
#pragma unroll
    for (int r = 0; r < 16; ++r) {
        float bv = best[r];
        int bi = bidx[r];
#pragma unroll
        for (int d = 1; d < 32; d <<= 1) {
            float ov = __shfl_xor(bv, d);
            int oi = __shfl_xor(bi, d);
            if (ov > bv || (ov == bv && oi < bi)) {  // smaller idx on tie
                bv = ov;
                bi = oi;
            }
        }
        if (col == 0) {
            const int row = row_base + (r & 3) + 8 * (r >> 2) + 4 * half_;
            pbest[(size_t)split * N_ROWS + row] = bv;
            pidx[(size_t)split * N_ROWS + row] = bi;
        }
    }
}

// ---------------------------------------------------------------------------
// Kernel 2: combine splits, gather quantize rows, write index-as-float.
// One thread per (row, float4-chunk): t in [0, N_ROWS*16).
// ---------------------------------------------------------------------------
__global__ void combine_kernel(const float* __restrict__ pbest,
                               const int* __restrict__ pidx,
                               const float* __restrict__ embed,
                               float* __restrict__ out) {
    const int t = blockIdx.x * blockDim.x + threadIdx.x;
    const int row = t >> 4;
    const int q = t & 15;
    if (row >= N_ROWS) return;

    float best = -INFINITY;
    int bi = 0;
#pragma unroll
    for (int s = 0; s < SPLITS; ++s) {
        float b = pbest[(size_t)s * N_ROWS + row];
        int i = pidx[(size_t)s * N_ROWS + row];
        if (b > best) {  // splits ascending in code; strict > keeps earliest
            best = b;
            bi = i;
        }
    }

    const float4* e4 = reinterpret_cast<const float4*>(embed);
    float4 v = e4[(size_t)bi * (DIM / 4) + q];
    reinterpret_cast<float4*>(out)[(size_t)row * (DIM / 4) + q] = v;
    if (q == 0) {
        out[(size_t)QUANT_ELEMS + row] = (float)bi;  // index as float
    }
}

// ---------------------------------------------------------------------------
extern "C" void kernel_launch(void* const* d_in, const int* in_sizes, int n_in,
                              void* d_out, int out_size, void* d_ws,
                              size_t ws_size, hipStream_t stream) {
    const float* x = (const float*)d_in[0];
    const float* embed = (const float*)d_in[1];
    float* out = (float*)d_out;

    // ws: sq 16KB | ehi 512KB | elo 512KB | pbest 384KB | pidx 384KB
    char* ws = (char*)d_ws;
    float* sq = (float*)ws;
    half8* ehi = (half8*)(ws + 16384);
    half8* elo = (half8*)(ws + 16384 + 524288);
    float* pbest = (float*)(ws + 16384 + 2 * 524288);
    int* pidx = (int*)(ws + 16384 + 2 * 524288 + SPLITS * N_ROWS * 4);

    prep_kernel<<<TILES_TOTAL, 256, 0, stream>>>(embed, sq, ehi, elo);

    dim3 grid(N_ROWS / 128, SPLITS);
    fused_dist_argmax32<<<grid, 256, 0, stream>>>(x, sq, ehi, elo, pbest,
                                                  pidx);

    const int combine_threads = N_ROWS * (DIM / 4);
    combine_kernel<<<(combine_threads + 255) / 256, 256, 0, stream>>>(
        pbest, pidx, embed, out);
}